// Round 1
// baseline (305.355 us; speedup 1.0000x reference)
//
#include <hip/hip_runtime.h>
#include <cstddef>

// Problem constants
constexpr int Bn = 8;     // batch
constexpr int Cn = 128;   // in channels
constexpr int En = 128;   // embedding (height)
constexpr int Tn = 128;   // time
constexpr int On = 256;   // out channels
constexpr int Gn = 4;     // groups
constexpr int KWn = 9;    // kernel width
constexpr int Dn = Cn / Gn;   // 32 depth per group
constexpr int Nn = On / Gn;   // 64 filters per group
constexpr int Fn = 64;        // pooled height out: (128-2)/2+1
constexpr int TP = Tn + 8;    // padded time = 136
constexpr int DC = 4;         // d-chunk for weight staging

// out[b, o, f, t] = leakyrelu( sum_{e in {2f,2f+1}} sum_{d<32} sum_{w<9}
//                    x[b, g*32+d, e, t+w-4] * W[o, d, e, w] ),  g = o/64
__global__ __launch_bounds__(256)
void lconv_kernel(const float* __restrict__ x,
                  const float* __restrict__ w,
                  float* __restrict__ out)
{
    const int f = blockIdx.x;   // 0..63
    const int g = blockIdx.y;   // 0..3
    const int b = blockIdx.z;   // 0..7
    const int e0 = 2 * f;

    __shared__ __align__(16) float xs[2][Dn][TP];       // 34816 B
    __shared__ __align__(16) float ws[2][DC][KWn][Nn];  // 18432 B

    const int tid = threadIdx.x;

    // ---- stage x slice: xs[e][d][tp] = x[b, g*32+d, e0+e, tp-4] (0-padded) ----
    for (int idx = tid; idx < 2 * Dn * TP; idx += 256) {
        int tp = idx % TP;
        int r  = idx / TP;
        int d  = r & (Dn - 1);
        int e  = r >> 5;
        float v = 0.0f;
        int t = tp - 4;
        if (t >= 0 && t < Tn) {
            v = x[(((size_t)b * Cn + g * Dn + d) * En + (e0 + e)) * Tn + t];
        }
        xs[e][d][tp] = v;
    }

    const int nb = tid >> 5;   // 0..7 : 8 n-values per thread
    const int tb = tid & 31;   // 0..31: 4 t-values per thread
    const int t0 = tb * 4;

    float acc[8][4];
    #pragma unroll
    for (int i = 0; i < 8; ++i)
        #pragma unroll
        for (int j = 0; j < 4; ++j) acc[i][j] = 0.0f;

    // weight staging mapping: one (dd, n) pair per thread
    const int sdd = tid >> 6;   // 0..3
    const int sn  = tid & 63;   // 0..63

    for (int dc = 0; dc < Dn / DC; ++dc) {
        __syncthreads();
        // stage W[g*64+n, dc*DC+dd, e0..e0+1, 0..8] -> ws[e][dd][kw][n]
        {
            const int d = dc * DC + sdd;
            const int o = g * Nn + sn;
            const float* wp = &w[(((size_t)o * Dn + d) * En + e0) * KWn];
            #pragma unroll
            for (int e = 0; e < 2; ++e)
                #pragma unroll
                for (int kw = 0; kw < KWn; ++kw)
                    ws[e][sdd][kw][sn] = wp[e * KWn + kw];
        }
        __syncthreads();

        #pragma unroll
        for (int e = 0; e < 2; ++e) {
            #pragma unroll
            for (int dd = 0; dd < DC; ++dd) {
                const int d = dc * DC + dd;
                // x window: xs[e][d][t0 .. t0+11]
                const float4* xr = reinterpret_cast<const float4*>(&xs[e][d][t0]);
                float4 xv0 = xr[0], xv1 = xr[1], xv2 = xr[2];
                float xw[12] = {xv0.x, xv0.y, xv0.z, xv0.w,
                                xv1.x, xv1.y, xv1.z, xv1.w,
                                xv2.x, xv2.y, xv2.z, xv2.w};
                #pragma unroll
                for (int kw = 0; kw < KWn; ++kw) {
                    const float4* wr = reinterpret_cast<const float4*>(&ws[e][dd][kw][nb * 8]);
                    float4 wv0 = wr[0], wv1 = wr[1];
                    float wvv[8] = {wv0.x, wv0.y, wv0.z, wv0.w,
                                    wv1.x, wv1.y, wv1.z, wv1.w};
                    #pragma unroll
                    for (int i = 0; i < 8; ++i)
                        #pragma unroll
                        for (int j = 0; j < 4; ++j)
                            acc[i][j] = fmaf(wvv[i], xw[j + kw], acc[i][j]);
                }
            }
        }
    }

    // ---- epilogue: LeakyReLU + coalesced float4 store ----
    #pragma unroll
    for (int i = 0; i < 8; ++i) {
        const int o = g * Nn + nb * 8 + i;
        float4 v;
        v.x = acc[i][0] >= 0.0f ? acc[i][0] : 0.01f * acc[i][0];
        v.y = acc[i][1] >= 0.0f ? acc[i][1] : 0.01f * acc[i][1];
        v.z = acc[i][2] >= 0.0f ? acc[i][2] : 0.01f * acc[i][2];
        v.w = acc[i][3] >= 0.0f ? acc[i][3] : 0.01f * acc[i][3];
        *reinterpret_cast<float4*>(&out[(((size_t)b * On + o) * Fn + f) * Tn + t0]) = v;
    }
}

extern "C" void kernel_launch(void* const* d_in, const int* in_sizes, int n_in,
                              void* d_out, int out_size, void* d_ws, size_t ws_size,
                              hipStream_t stream)
{
    const float* x = (const float*)d_in[0];   // (8, 128, 128, 128) fp32
    const float* w = (const float*)d_in[1];   // (256, 32, 128, 9) fp32
    float* out = (float*)d_out;               // (8, 256, 64, 128) fp32

    dim3 grid(Fn, Gn, Bn);   // (64, 4, 8)
    dim3 block(256);
    hipLaunchKernelGGL(lconv_kernel, grid, block, 0, stream, x, w, out);
}

// Round 3
// 61.697 us; speedup vs baseline: 4.9493x; 4.9493x over previous
//
#include <hip/hip_runtime.h>
#include <cstddef>

typedef __attribute__((ext_vector_type(8))) short short8v;
typedef __attribute__((ext_vector_type(4))) float f32x4;

__device__ __forceinline__ unsigned short f2bf(float f) {
    unsigned u = __float_as_uint(f);
    u = (u + 0x7FFFu + ((u >> 16) & 1u)) >> 16;
    return (unsigned short)u;
}

// ---- prep: W[o][d][e][w] fp32 -> Wb[g][e][n][w*32+d] bf16 (in d_ws) ----
// block per o (256 blocks x 256 threads), LDS transpose with XOR swizzle.
__global__ __launch_bounds__(256) void prep_w(const float* __restrict__ w,
                                              unsigned short* __restrict__ wb)
{
    const int o   = blockIdx.x;      // 0..255
    const int tid = threadIdx.x;
    __shared__ unsigned short ls[36864];   // 72 KiB
    const float* wo = w + (size_t)o * 36864;

    // phase 1: coalesced float4 read, convert, swizzled LDS store
    // invariant: ls[f ^ (2*(f/1152))] = bf16(w_flat[f])
    for (int i = 0; i < 36; ++i) {
        int idx4 = tid + i * 256;                   // float4 id 0..9215
        float4 v = reinterpret_cast<const float4*>(wo)[idx4];
        int f0 = idx4 * 4;
        int d  = f0 / 1152;                          // same d for all 4 (1152 % 4 == 0)
        int sw = (d & 31) << 1;
        int s0 = f0 ^ sw;                            // even; bit0 untouched
        ushort2 p0; p0.x = f2bf(v.x); p0.y = f2bf(v.y);
        ushort2 p1; p1.x = f2bf(v.z); p1.y = f2bf(v.w);
        *reinterpret_cast<ushort2*>(&ls[s0])     = p0;
        *reinterpret_cast<ushort2*>(&ls[s0 ^ 2]) = p1;
    }
    __syncthreads();

    // phase 2: gather d-contiguous runs, coalesced 16B global writes
    const int g = o >> 6, n = o & 63;
    for (int i = 0; i < 18; ++i) {
        int c  = tid + i * 256;                      // 8-elem chunk id 0..4607
        int q0 = c * 8;
        int e  = q0 / 288;
        int r  = q0 - e * 288;                       // w*32 + d0 (d0 in {0,8,16,24})
        int wi = r >> 5;
        int d0 = r & 31;
        short8v vv;
        #pragma unroll
        for (int j = 0; j < 8; ++j) {
            int d = d0 + j;
            int fq = 1152 * d + 9 * e + wi;
            vv[j] = (short)ls[fq ^ ((d & 31) << 1)];
        }
        size_t oi = (((size_t)(g * 128 + e) * 64 + n) * 288 + (size_t)r);
        *reinterpret_cast<short8v*>(&wb[oi]) = vv;
    }
}

// ---- main: per (b,g,f) 64n x 128t GEMM, K = 576 = (e2,w9,d32), bf16 MFMA ----
// x staged time-major: xs[e][tp][d] with pitch 40 shorts (80B, 16B-aligned)
// so BOTH A and B fragments are plain contiguous ds_read_b128 (same k map).
__global__ __launch_bounds__(256, 2) void lconv_mfma(const float* __restrict__ x,
                                                     const unsigned short* __restrict__ wb,
                                                     float* __restrict__ out)
{
    // XCD-chunked swizzle: the 8 b-blocks sharing a weight slice -> same XCD
    int bid = blockIdx.x;                  // 0..2047
    int c   = (bid & 7) * 256 + (bid >> 3);
    const int b = c & 7;
    const int f = (c >> 3) & 63;
    const int g = c >> 9;
    const int e0 = 2 * f;

    const int tid  = threadIdx.x;
    const int lane = tid & 63;
    const int wv   = tid >> 6;     // wave id 0..3 -> t range [wv*32, wv*32+32)
    const int li   = lane & 15;
    const int hi   = lane >> 4;

    __shared__ __align__(16) unsigned short xs[2 * 144 * 40];  // 23040 B
    __shared__ __align__(16) unsigned short ws[64 * 288];      // 36864 B  (total 59904)

    // ---- stage x: coalesced float4 global read, scalar LDS writes (transpose) ----
    #pragma unroll
    for (int i = 0; i < 8; ++i) {
        int r   = tid + i * 256;            // 0..2047 : e(2) x d(32) x t4(32)
        int e   = r >> 10;
        int rem = r & 1023;
        int d   = rem >> 5;
        int t4  = rem & 31;
        const float4 v = *reinterpret_cast<const float4*>(
            &x[(((size_t)(b * 128 + g * 32 + d)) * 128 + (e0 + e)) * 128 + t4 * 4]);
        int tp0 = t4 * 4 + 4;               // tp = t + 4 (left pad 4)
        unsigned short* p = &xs[(e * 144 + tp0) * 40 + d];
        p[0]   = f2bf(v.x);
        p[40]  = f2bf(v.y);
        p[80]  = f2bf(v.z);
        p[120] = f2bf(v.w);
    }
    // zero pads: tp in {0..3} and {132..135}, all d
    {
        int p2 = tid;
        for (int i = 0; i < 2; ++i, p2 += 256) {
            int e = p2 >> 8;
            int j = (p2 >> 5) & 7;
            int d = p2 & 31;
            int tp = (j < 4) ? j : (128 + j);
            xs[(e * 144 + tp) * 40 + d] = 0;
        }
    }

    f32x4 acc[4][2];
    #pragma unroll
    for (int nt = 0; nt < 4; ++nt)
        #pragma unroll
        for (int tt = 0; tt < 2; ++tt)
            acc[nt][tt] = (f32x4){0.f, 0.f, 0.f, 0.f};

    for (int ec = 0; ec < 2; ++ec) {
        __syncthreads();
        // stage weight slice (g, e0+ec): 64x288 bf16, contiguous in Wb
        const unsigned short* src = wb + (size_t)((g * 128) + e0 + ec) * (64 * 288);
        #pragma unroll
        for (int i = 0; i < 9; ++i) {
            int u = tid + i * 256;          // short8 unit 0..2303
            *reinterpret_cast<short8v*>(&ws[u * 8]) =
                *reinterpret_cast<const short8v*>(&src[u * 8]);
        }
        __syncthreads();

        #pragma unroll 3
        for (int w9 = 0; w9 < 9; ++w9) {
            // A-frags (weights): n = nt*16 + li, k-elems = w9*32 + hi*8 + j
            short8v wa[4];
            #pragma unroll
            for (int nt = 0; nt < 4; ++nt)
                wa[nt] = *reinterpret_cast<const short8v*>(
                    &ws[(nt * 16 + li) * 288 + w9 * 32 + hi * 8]);

            // B-frags (x): col t = wv*32 + tt*16 + li, k-elems = d = hi*8 + j
            short8v bx[2];
            #pragma unroll
            for (int tt = 0; tt < 2; ++tt) {
                int tp = wv * 32 + tt * 16 + li + w9;   // t + w9 (padded index)
                bx[tt] = *reinterpret_cast<const short8v*>(
                    &xs[(ec * 144 + tp) * 40 + hi * 8]);
            }

            #pragma unroll
            for (int nt = 0; nt < 4; ++nt)
                #pragma unroll
                for (int tt = 0; tt < 2; ++tt)
                    acc[nt][tt] = __builtin_amdgcn_mfma_f32_16x16x32_bf16(
                        wa[nt], bx[tt], acc[nt][tt], 0, 0, 0);
        }
    }

    // ---- epilogue: LeakyReLU + store (C: col=lane&15 -> t, row=(lane>>4)*4+j -> n) ----
    #pragma unroll
    for (int nt = 0; nt < 4; ++nt) {
        #pragma unroll
        for (int tt = 0; tt < 2; ++tt) {
            #pragma unroll
            for (int j = 0; j < 4; ++j) {
                float v = acc[nt][tt][j];
                v = (v >= 0.f) ? v : 0.01f * v;
                int n = nt * 16 + hi * 4 + j;
                int t = wv * 32 + tt * 16 + li;
                out[(((size_t)(b * 256 + g * 64 + n)) * 64 + f) * 128 + t] = v;
            }
        }
    }
}

extern "C" void kernel_launch(void* const* d_in, const int* in_sizes, int n_in,
                              void* d_out, int out_size, void* d_ws, size_t ws_size,
                              hipStream_t stream)
{
    const float* x = (const float*)d_in[0];           // (8,128,128,128) fp32
    const float* w = (const float*)d_in[1];           // (256,32,128,9) fp32
    float* out = (float*)d_out;                       // (8,256,64,128) fp32
    unsigned short* wb = (unsigned short*)d_ws;       // 256*128*288 bf16 = 18.9 MB

    hipLaunchKernelGGL(prep_w, dim3(256), dim3(256), 0, stream, w, wb);
    hipLaunchKernelGGL(lconv_mfma, dim3(2048), dim3(256), 0, stream, x, wb, out);
}